// Round 3
// 599.592 us; speedup vs baseline: 1.0180x; 1.0180x over previous
//
#include <hip/hip_runtime.h>
#include <hip/hip_fp16.h>

// Problem constants
#define NB    16
#define CH    64
#define HWTOT 65536
#define LSEL  900
#define LPAD  912   // 57*16, row pad for 16-row MFMA tiles
#define KPAD  928   // 29*32, K pad for 16x16x32 MFMA

typedef _Float16 half8  __attribute__((ext_vector_type(8)));
typedef float    float4v __attribute__((ext_vector_type(4)));

// Workspace layout (bytes). Total ~8.6 MB.
#define OFF_HIST 0u         // NB*65*4 = 4160
#define OFF_Z    5120u      // NB*HWTOT (uchar) = 1 MB
#define OFF_IDX  1053696u   // NB*LSEL*4
#define OFF_Q    1111296u   // NB*CH*LSEL*4 = 3.69 MB
#define OFF_E1   4797696u   // NB*LPAD*32*2 (fp16, [b][l][c])
#define OFF_E2   5731584u   // NB*LPAD*32*2 (fp16, [b][m][c])
#define OFF_EA   6665472u   // NB*CH*KPAD*2 (fp16, [b][c][m])

// K1: copy x -> out, per-position sign count z, per-batch histogram of z.
__global__ void k_copy_count(const float* __restrict__ x, float* __restrict__ out,
                             uchar4* __restrict__ z4, int* __restrict__ hist) {
    __shared__ int sh[65];
    int tid = threadIdx.x;
    if (tid < 65) sh[tid] = 0;
    __syncthreads();
    int b  = blockIdx.x >> 6;                      // 64 blocks per batch
    int wi = ((blockIdx.x & 63) << 8) | tid;       // 0..16383 (HW/4)
    const float4* xb = (const float4*)x + (size_t)b * CH * (HWTOT/4) + wi;
    float4*       ob = (float4*)out    + (size_t)b * CH * (HWTOT/4) + wi;
    int c0=0, c1=0, c2=0, c3=0;
    for (int c = 0; c < CH; ++c) {
        float4 v = xb[(size_t)c * (HWTOT/4)];
        ob[(size_t)c * (HWTOT/4)] = v;
        c0 += (v.x >= 0.f); c1 += (v.y >= 0.f);
        c2 += (v.z >= 0.f); c3 += (v.w >= 0.f);
    }
    z4[(size_t)b * (HWTOT/4) + wi] = make_uchar4((unsigned char)c0, (unsigned char)c1,
                                                 (unsigned char)c2, (unsigned char)c3);
    atomicAdd(&sh[c0], 1); atomicAdd(&sh[c1], 1);
    atomicAdd(&sh[c2], 1); atomicAdd(&sh[c3], 1);
    __syncthreads();
    if (tid < 65) atomicAdd(&hist[b*65 + tid], sh[tid]);
}

// K2: per batch, compute threshold t / remainder r inline from hist, then
// select {z<t} plus the lowest-index r positions with z==t.
// One block of 1024 threads scans 16 ordered chunks of 4096 positions.
__global__ void k_select(const uchar4* __restrict__ z4, const int* __restrict__ hist,
                         int* __restrict__ idx) {
    int b = blockIdx.x;
    // threshold scan (uniform across block; small L2-resident table)
    int cum = 0, t = 64, r = 0;
    for (int k = 0; k < 65; ++k) {
        int h = hist[b*65 + k];
        if (cum + h > LSEL) { t = k; r = LSEL - cum; break; }
        cum += h;
    }
    __shared__ int wsum[16];
    __shared__ int slot;
    int tid = threadIdx.x, lane = tid & 63, w = tid >> 6;
    if (tid == 0) slot = 0;
    __syncthreads();
    int run_eq = 0;
    const uchar4* zb = z4 + (size_t)b * (HWTOT/4);
    for (int chunk = 0; chunk < 16; ++chunk) {
        int i4 = (chunk << 10) | tid;
        uchar4 v = zb[i4];
        int e0 = (v.x == t), e1 = (v.y == t), e2 = (v.z == t), e3 = (v.w == t);
        int me = e0 + e1 + e2 + e3;
        int s = me;
        #pragma unroll
        for (int d = 1; d < 64; d <<= 1) {
            int u = __shfl_up(s, d, 64);
            if (lane >= d) s += u;
        }
        if (lane == 63) wsum[w] = s;
        __syncthreads();
        int woff = 0, tot = 0;
        for (int j = 0; j < 16; ++j) { int xx = wsum[j]; tot += xx; if (j < w) woff += xx; }
        int before = run_eq + woff + (s - me);
        int pos = i4 << 2;
        if ((v.x < t) || (e0 && (before            < r))) idx[b*LSEL + atomicAdd(&slot,1)] = pos;
        if ((v.y < t) || (e1 && (before+e0         < r))) idx[b*LSEL + atomicAdd(&slot,1)] = pos+1;
        if ((v.z < t) || (e2 && (before+e0+e1      < r))) idx[b*LSEL + atomicAdd(&slot,1)] = pos+2;
        if ((v.w < t) || (e3 && (before+e0+e1+e2   < r))) idx[b*LSEL + atomicAdd(&slot,1)] = pos+3;
        run_eq += tot;
        __syncthreads();
    }
}

// K3: gather q[b][c][l] = x[b][c][idx[b][l]]
__global__ void k_gather(const float* __restrict__ x, const int* __restrict__ idx,
                         float* __restrict__ q) {
    int g = blockIdx.x * 256 + threadIdx.x;   // exactly NB*CH*LSEL = 921600
    int l = g % LSEL;
    int t = g / LSEL;
    int c = t & 63, b = t >> 6;
    int p = idx[b*LSEL + l];
    q[(size_t)(b*CH + c)*LSEL + l] = x[(size_t)(b*CH + c)*HWTOT + p];
}

// K4 (fused): blocks [0,3648): e1T/e2T (fp16, [b][l][32], l padded to 912, pad rows 0)
//             blocks [3648,4672): eah (fp16, [b][c][m], m padded to 928, pad cols 0)
#define E12_BLOCKS 3648
__global__ void k_e(const float* __restrict__ q,
                    const float* __restrict__ W1, const float* __restrict__ b1, const float* __restrict__ a1,
                    const float* __restrict__ W2, const float* __restrict__ b2, const float* __restrict__ a2,
                    const float* __restrict__ Wa, const float* __restrict__ ba, const float* __restrict__ aa,
                    _Float16* __restrict__ e1T, _Float16* __restrict__ e2T,
                    _Float16* __restrict__ eah) {
    if (blockIdx.x < E12_BLOCKS) {
        int g = blockIdx.x * 256 + threadIdx.x;   // exactly NB*2*LPAD*32 = 933888
        int c = g & 31;
        int t = g >> 5;
        int l = t % LPAD; t /= LPAD;
        int which = t & 1, b = t >> 1;
        const float* W = which ? W2 : W1;
        float bias = which ? b2[c] : b1[c];
        float al   = which ? a2[0] : a1[0];
        float acc = 0.f;
        if (l < LSEL) {
            acc = bias;
            const float* qb = q + (size_t)b * CH * LSEL + l;
            for (int k = 0; k < CH; ++k) acc += W[c*CH + k] * qb[(size_t)k * LSEL];
            acc = (acc >= 0.f) ? acc : al * acc;
        }
        _Float16* e = which ? e2T : e1T;
        e[((size_t)b * LPAD + l) * 32 + c] = (_Float16)acc;
    } else {
        int bid = blockIdx.x - E12_BLOCKS;        // 0..1023
        int c = bid & 63, b = bid >> 6;
        float bias = ba[c], al = aa[0];
        for (int m = threadIdx.x; m < KPAD; m += 256) {
            float acc = 0.f;
            if (m < LSEL) {
                acc = bias;
                const float* qb = q + (size_t)b * CH * LSEL + m;
                for (int k = 0; k < CH; ++k) acc += Wa[c*CH + k] * qb[(size_t)k * LSEL];
                acc = (acc >= 0.f) ? acc : al * acc;
            }
            eah[((size_t)b * CH + c) * KPAD + m] = (_Float16)acc;
        }
    }
}

// K5: fused attention per 16-row tile. GEMM1 (S=e1^T e2) in registers via MFMA,
// softmax stats cross-lane, unnormalized P -> LDS fp16, GEMM2 (P @ ea^T) via MFMA
// with two accumulator chains, scale by 1/rowsum, add q, scatter into out.
__global__ __launch_bounds__(256, 2)
void k_attn(const _Float16* __restrict__ e1T, const _Float16* __restrict__ e2T,
            const _Float16* __restrict__ eah, const float* __restrict__ q,
            const int* __restrict__ idx, float* __restrict__ out) {
    int b = blockIdx.x / 57, tile = blockIdx.x % 57;
    int l0 = tile * 16;
    int tid = threadIdx.x, lane = tid & 63, w = tid >> 6;
    int n16 = lane & 15, quad = lane >> 4;

    __shared__ _Float16 pbuf[16][KPAD];
    __shared__ float rmx[4][16], rsm[4][16], rstat[16], rinv[16];

    // zero P pad columns 912..927 (avoid NaN garbage entering MFMA)
    pbuf[tid >> 4][LPAD + (tid & 15)] = (_Float16)0.f;

    // A-frag for GEMM1: A[m=lane&15][k=quad*8+j] = e1[l0+m][c-chunk]
    half8 afrag = *(const half8*)(e1T + ((size_t)b*LPAD + l0 + n16)*32 + quad*8);

    // GEMM1: wave w owns m-tiles t = w + 4*i
    float4v sv[15];
    const int nt = (w == 0) ? 15 : 14;   // 57 tiles total
    #pragma unroll
    for (int i = 0; i < 15; ++i) {
        if (i < nt) {
            int t = w + 4*i;
            half8 bfrag = *(const half8*)(e2T + ((size_t)b*LPAD + t*16 + n16)*32 + quad*8);
            float4v z = {0.f, 0.f, 0.f, 0.f};
            sv[i] = __builtin_amdgcn_mfma_f32_16x16x32_f16(afrag, bfrag, z, 0, 0, 0);
        }
    }
    // mask pad columns m=900..911 (tile 56, owned by wave 0 at i=14)
    if (w == 0 && n16 >= 4) { sv[14][0] = sv[14][1] = sv[14][2] = sv[14][3] = -1e30f; }

    // row max (per lane over own tiles, then xor-reduce across the 16 col-lanes)
    float mv0 = -1e30f, mv1 = -1e30f, mv2 = -1e30f, mv3 = -1e30f;
    #pragma unroll
    for (int i = 0; i < 15; ++i) if (i < nt) {
        mv0 = fmaxf(mv0, sv[i][0]); mv1 = fmaxf(mv1, sv[i][1]);
        mv2 = fmaxf(mv2, sv[i][2]); mv3 = fmaxf(mv3, sv[i][3]);
    }
    #pragma unroll
    for (int d = 1; d < 16; d <<= 1) {
        mv0 = fmaxf(mv0, __shfl_xor(mv0, d, 64));
        mv1 = fmaxf(mv1, __shfl_xor(mv1, d, 64));
        mv2 = fmaxf(mv2, __shfl_xor(mv2, d, 64));
        mv3 = fmaxf(mv3, __shfl_xor(mv3, d, 64));
    }
    if (n16 == 0) {
        rmx[w][quad*4+0] = mv0; rmx[w][quad*4+1] = mv1;
        rmx[w][quad*4+2] = mv2; rmx[w][quad*4+3] = mv3;
    }
    __syncthreads();
    if (tid < 16)
        rstat[tid] = fmaxf(fmaxf(rmx[0][tid], rmx[1][tid]), fmaxf(rmx[2][tid], rmx[3][tid]));
    __syncthreads();
    float rm0 = rstat[quad*4+0], rm1 = rstat[quad*4+1];
    float rm2 = rstat[quad*4+2], rm3 = rstat[quad*4+3];

    // exp, write unnormalized P to LDS, partial row sums
    float s0 = 0.f, s1 = 0.f, s2 = 0.f, s3 = 0.f;
    #pragma unroll
    for (int i = 0; i < 15; ++i) if (i < nt) {
        int m = (w + 4*i)*16 + n16;
        float e0 = __expf(sv[i][0] - rm0); s0 += e0; pbuf[quad*4+0][m] = (_Float16)e0;
        float e1 = __expf(sv[i][1] - rm1); s1 += e1; pbuf[quad*4+1][m] = (_Float16)e1;
        float e2 = __expf(sv[i][2] - rm2); s2 += e2; pbuf[quad*4+2][m] = (_Float16)e2;
        float e3 = __expf(sv[i][3] - rm3); s3 += e3; pbuf[quad*4+3][m] = (_Float16)e3;
    }
    #pragma unroll
    for (int d = 1; d < 16; d <<= 1) {
        s0 += __shfl_xor(s0, d, 64); s1 += __shfl_xor(s1, d, 64);
        s2 += __shfl_xor(s2, d, 64); s3 += __shfl_xor(s3, d, 64);
    }
    if (n16 == 0) {
        rsm[w][quad*4+0] = s0; rsm[w][quad*4+1] = s1;
        rsm[w][quad*4+2] = s2; rsm[w][quad*4+3] = s3;
    }
    __syncthreads();
    if (tid < 16)
        rinv[tid] = 1.f / (rsm[0][tid] + rsm[1][tid] + rsm[2][tid] + rsm[3][tid]);
    __syncthreads();   // also guarantees all pbuf writes are visible

    // GEMM2: wave w owns output col-tile c0 = 16*w. K = 928 = 28*32 + 32.
    // Two accumulator chains to halve exposed dependent-MFMA latency.
    float4v acc0 = {0.f, 0.f, 0.f, 0.f}, acc1 = {0.f, 0.f, 0.f, 0.f};
    const _Float16* eb = eah + ((size_t)b*CH + w*16 + n16)*KPAD + quad*8;
    const _Float16* pb = &pbuf[n16][quad*8];
    #pragma unroll
    for (int k0 = 0; k0 < 896; k0 += 64) {
        half8 af0 = *(const half8*)(pb + k0);
        half8 bf0 = *(const half8*)(eb + k0);
        acc0 = __builtin_amdgcn_mfma_f32_16x16x32_f16(af0, bf0, acc0, 0, 0, 0);
        half8 af1 = *(const half8*)(pb + k0 + 32);
        half8 bf1 = *(const half8*)(eb + k0 + 32);
        acc1 = __builtin_amdgcn_mfma_f32_16x16x32_f16(af1, bf1, acc1, 0, 0, 0);
    }
    {
        half8 af = *(const half8*)(pb + 896);
        half8 bf = *(const half8*)(eb + 896);
        acc0 = __builtin_amdgcn_mfma_f32_16x16x32_f16(af, bf, acc0, 0, 0, 0);
    }

    // epilogue: normalize, add q, scatter
    int c = w*16 + n16;
    const float* qrow = q + (size_t)(b*CH + c)*LSEL;
    float* orow = out + (size_t)(b*CH + c)*HWTOT;
    const int* irow = idx + b*LSEL;
    #pragma unroll
    for (int v = 0; v < 4; ++v) {
        int lr = quad*4 + v;
        int l = l0 + lr;
        if (l < LSEL) {
            float val = (acc0[v] + acc1[v]) * rinv[lr] + qrow[l];
            orow[irow[l]] = val;
        }
    }
}

extern "C" void kernel_launch(void* const* d_in, const int* in_sizes, int n_in,
                              void* d_out, int out_size, void* d_ws, size_t ws_size,
                              hipStream_t stream) {
    const float* x  = (const float*)d_in[0];
    const float* W1 = (const float*)d_in[1];
    const float* b1 = (const float*)d_in[2];
    const float* a1 = (const float*)d_in[3];
    const float* W2 = (const float*)d_in[4];
    const float* b2 = (const float*)d_in[5];
    const float* a2 = (const float*)d_in[6];
    const float* Wa = (const float*)d_in[7];
    const float* ba = (const float*)d_in[8];
    const float* aa = (const float*)d_in[9];
    float* out = (float*)d_out;
    char* ws = (char*)d_ws;

    int*      hist = (int*)     (ws + OFF_HIST);
    uchar4*   z4   = (uchar4*)  (ws + OFF_Z);
    int*      idx  = (int*)     (ws + OFF_IDX);
    float*    q    = (float*)   (ws + OFF_Q);
    _Float16* e1T  = (_Float16*)(ws + OFF_E1);
    _Float16* e2T  = (_Float16*)(ws + OFF_E2);
    _Float16* eah  = (_Float16*)(ws + OFF_EA);

    hipMemsetAsync(hist, 0, NB*65*sizeof(int), stream);
    k_copy_count<<<NB*64, 256, 0, stream>>>(x, out, z4, hist);
    k_select<<<NB, 1024, 0, stream>>>(z4, hist, idx);
    k_gather<<<3600, 256, 0, stream>>>(x, idx, q);
    k_e<<<E12_BLOCKS + NB*CH, 256, 0, stream>>>(q, W1, b1, a1, W2, b2, a2,
                                                Wa, ba, aa, e1T, e2T, eah);
    k_attn<<<NB*57, 256, 0, stream>>>(e1T, e2T, eah, q, idx, out);
}

// Round 4
// 587.462 us; speedup vs baseline: 1.0390x; 1.0206x over previous
//
#include <hip/hip_runtime.h>
#include <hip/hip_fp16.h>

// Problem constants
#define NB    16
#define CH    64
#define HWTOT 65536
#define LSEL  900
#define LPAD  912   // 57*16, row pad for 16-row MFMA tiles
#define KPAD  928   // 29*32, K pad for 16x16x32 MFMA

typedef _Float16 half8  __attribute__((ext_vector_type(8)));
typedef float    float4v __attribute__((ext_vector_type(4)));

// Workspace layout (bytes). Total ~5.2 MB.
#define OFF_HIST2 0u         // NB*64*65*4 = 266240 (per-block hist slots)
#define OFF_Z     270336u    // NB*HWTOT (uchar) = 1 MB
#define OFF_IDX   1318912u   // NB*LSEL*4 = 57600
#define OFF_E1    1376512u   // NB*LPAD*32*2 (fp16, [b][l][c]) = 933888
#define OFF_E2    2310400u   // NB*LPAD*32*2 (fp16, [b][m][c]) = 933888
#define OFF_EA    3244288u   // NB*CH*KPAD*2 (fp16, [b][c][m]) = 1900544

// K1: copy x -> out, per-position sign count z, per-block histogram slot
// (no global atomics, no memset needed).
__global__ void k_copy_count(const float* __restrict__ x, float* __restrict__ out,
                             uchar4* __restrict__ z4, int* __restrict__ hist2) {
    __shared__ int sh[65];
    int tid = threadIdx.x;
    if (tid < 65) sh[tid] = 0;
    __syncthreads();
    int b  = blockIdx.x >> 6;                      // 64 blocks per batch
    int wi = ((blockIdx.x & 63) << 8) | tid;       // 0..16383 (HW/4)
    const float4* xb = (const float4*)x + (size_t)b * CH * (HWTOT/4) + wi;
    float4*       ob = (float4*)out    + (size_t)b * CH * (HWTOT/4) + wi;
    int c0=0, c1=0, c2=0, c3=0;
    for (int c = 0; c < CH; ++c) {
        float4 v = xb[(size_t)c * (HWTOT/4)];
        ob[(size_t)c * (HWTOT/4)] = v;
        c0 += (v.x >= 0.f); c1 += (v.y >= 0.f);
        c2 += (v.z >= 0.f); c3 += (v.w >= 0.f);
    }
    z4[(size_t)b * (HWTOT/4) + wi] = make_uchar4((unsigned char)c0, (unsigned char)c1,
                                                 (unsigned char)c2, (unsigned char)c3);
    atomicAdd(&sh[c0], 1); atomicAdd(&sh[c1], 1);
    atomicAdd(&sh[c2], 1); atomicAdd(&sh[c3], 1);
    __syncthreads();
    if (tid < 65) hist2[blockIdx.x * 65 + tid] = sh[tid];   // private slot, plain store
}

// K2: per batch: sum per-block hists -> threshold t / remainder r, then select
// {z<t} plus the lowest-index r positions with z==t.
// 16 waves; wave w owns chunk w (4096 positions) cached in 16 uint regs.
// Two barriers total; tie ranks via intra-wave scans (order = global index order).
__global__ void k_select(const unsigned int* __restrict__ zu_all,
                         const int* __restrict__ hist2, int* __restrict__ idx) {
    int b = blockIdx.x;
    int tid = threadIdx.x, lane = tid & 63, w = tid >> 6;
    __shared__ int shh[65];
    __shared__ int eqw[16];
    __shared__ int slot;
    if (tid == 0) slot = 0;
    if (tid < 65) {
        int h = 0;
        #pragma unroll
        for (int j = 0; j < 64; ++j) h += hist2[(b*64 + j)*65 + tid];
        shh[tid] = h;
    }
    __syncthreads();
    // threshold scan (uniform, from LDS)
    int cum = 0, t = 64, r = 0;
    for (int k = 0; k < 65; ++k) {
        int h = shh[k];
        if (cum + h > LSEL) { t = k; r = LSEL - cum; break; }
        cum += h;
    }
    // phase A: load chunk into regs, count ties
    const unsigned int* zu = zu_all + (size_t)b * (HWTOT/4);
    unsigned int zreg[16];
    int mecnt = 0;
    #pragma unroll
    for (int g = 0; g < 16; ++g) {
        unsigned int v = zu[(w << 10) | (g << 6) | lane];
        zreg[g] = v;
        mecnt += ((v      & 255u) == (unsigned)t);
        mecnt += (((v>>8)  & 255u) == (unsigned)t);
        mecnt += (((v>>16) & 255u) == (unsigned)t);
        mecnt += (((v>>24) & 255u) == (unsigned)t);
    }
    int tot = mecnt;
    #pragma unroll
    for (int d = 1; d < 64; d <<= 1) tot += __shfl_xor(tot, d, 64);
    if (lane == 0) eqw[w] = tot;
    __syncthreads();
    int eqbase = 0;
    #pragma unroll
    for (int j = 0; j < 16; ++j) { int xx = eqw[j]; if (j < w) eqbase += xx; }
    // phase B: emit (no barriers; intra-wave scans give stable tie ranks)
    int run = eqbase;
    #pragma unroll
    for (int g = 0; g < 16; ++g) {
        unsigned int v = zreg[g];
        int e0 = ((v      & 255u) == (unsigned)t);
        int e1 = (((v>>8)  & 255u) == (unsigned)t);
        int e2 = (((v>>16) & 255u) == (unsigned)t);
        int e3 = (((v>>24) & 255u) == (unsigned)t);
        int me = e0 + e1 + e2 + e3;
        int s = me;
        #pragma unroll
        for (int d = 1; d < 64; d <<= 1) {
            int u = __shfl_up(s, d, 64);
            if (lane >= d) s += u;
        }
        int before = run + (s - me);
        int i4 = (w << 10) | (g << 6) | lane;
        int pos = i4 << 2;
        int b0 = ((v      & 255u) < (unsigned)t);
        int b1 = (((v>>8)  & 255u) < (unsigned)t);
        int b2 = (((v>>16) & 255u) < (unsigned)t);
        int b3 = (((v>>24) & 255u) < (unsigned)t);
        if (b0 || (e0 && (before            < r))) idx[b*LSEL + atomicAdd(&slot,1)] = pos;
        if (b1 || (e1 && (before+e0         < r))) idx[b*LSEL + atomicAdd(&slot,1)] = pos+1;
        if (b2 || (e2 && (before+e0+e1      < r))) idx[b*LSEL + atomicAdd(&slot,1)] = pos+2;
        if (b3 || (e3 && (before+e0+e1+e2   < r))) idx[b*LSEL + atomicAdd(&slot,1)] = pos+3;
        run += __shfl(s, 63, 64);
    }
}

// K3 (fused gather + projections), gathers directly from x via idx:
//  blocks [0, 1824): e1+e2 combined (one thread computes both; shared x loads)
//                    layout [b][l][32] fp16, l padded to 912 (pad rows 0)
//  blocks [1824, 2752): eah, 4 c's per thread (shared x loads)
//                    layout [b][c][m] fp16, m padded to 928 (pad cols 0)
#define E12_BLOCKS 1824   // NB*LPAD*32/256
#define EA_BLOCKS  928    // NB*58 (m-tiles of 16)
__global__ void k_e(const float* __restrict__ x, const int* __restrict__ idx,
                    const float* __restrict__ W1, const float* __restrict__ b1, const float* __restrict__ a1,
                    const float* __restrict__ W2, const float* __restrict__ b2, const float* __restrict__ a2,
                    const float* __restrict__ Wa, const float* __restrict__ ba, const float* __restrict__ aa,
                    _Float16* __restrict__ e1T, _Float16* __restrict__ e2T,
                    _Float16* __restrict__ eah) {
    if (blockIdx.x < E12_BLOCKS) {
        int g = blockIdx.x * 256 + threadIdx.x;   // NB*LPAD*32 = 466944
        int c = g & 31;
        int t = g >> 5;
        int l = t % LPAD;
        int b = t / LPAD;
        float acc1 = 0.f, acc2 = 0.f;
        if (l < LSEL) {
            int p = idx[b*LSEL + l];
            acc1 = b1[c]; acc2 = b2[c];
            const float* xb = x + (size_t)b * CH * HWTOT + p;
            #pragma unroll 8
            for (int k = 0; k < CH; ++k) {
                float xv = xb[(size_t)k * HWTOT];
                acc1 += W1[c*CH + k] * xv;
                acc2 += W2[c*CH + k] * xv;
            }
            float al1 = a1[0], al2 = a2[0];
            acc1 = (acc1 >= 0.f) ? acc1 : al1 * acc1;
            acc2 = (acc2 >= 0.f) ? acc2 : al2 * acc2;
        }
        e1T[((size_t)b * LPAD + l) * 32 + c] = (_Float16)acc1;
        e2T[((size_t)b * LPAD + l) * 32 + c] = (_Float16)acc2;
    } else {
        int bid = blockIdx.x - E12_BLOCKS;        // 0..927
        int b  = bid / 58;
        int mt = bid % 58;
        int m  = mt*16 + (threadIdx.x & 15);
        int c0 = (threadIdx.x >> 4) * 4;          // 4 consecutive c per thread
        float a0 = 0.f, a1v = 0.f, a2v = 0.f, a3v = 0.f;
        if (m < LSEL) {
            int p = idx[b*LSEL + m];
            a0 = ba[c0]; a1v = ba[c0+1]; a2v = ba[c0+2]; a3v = ba[c0+3];
            const float* xb = x + (size_t)b * CH * HWTOT + p;
            #pragma unroll 8
            for (int k = 0; k < CH; ++k) {
                float xv = xb[(size_t)k * HWTOT];
                a0  += Wa[(c0  )*CH + k] * xv;
                a1v += Wa[(c0+1)*CH + k] * xv;
                a2v += Wa[(c0+2)*CH + k] * xv;
                a3v += Wa[(c0+3)*CH + k] * xv;
            }
            float al = aa[0];
            a0  = (a0  >= 0.f) ? a0  : al * a0;
            a1v = (a1v >= 0.f) ? a1v : al * a1v;
            a2v = (a2v >= 0.f) ? a2v : al * a2v;
            a3v = (a3v >= 0.f) ? a3v : al * a3v;
        }
        eah[((size_t)b * CH + c0  ) * KPAD + m] = (_Float16)a0;
        eah[((size_t)b * CH + c0+1) * KPAD + m] = (_Float16)a1v;
        eah[((size_t)b * CH + c0+2) * KPAD + m] = (_Float16)a2v;
        eah[((size_t)b * CH + c0+3) * KPAD + m] = (_Float16)a3v;
    }
}

// K4: fused attention per 16-row tile. GEMM1 (S=e1^T e2) in registers via MFMA,
// softmax stats cross-lane, unnormalized P -> LDS fp16, GEMM2 (P @ ea^T) via MFMA
// with two accumulator chains, scale by 1/rowsum, add x (== q), scatter into out.
__global__ __launch_bounds__(256, 2)
void k_attn(const _Float16* __restrict__ e1T, const _Float16* __restrict__ e2T,
            const _Float16* __restrict__ eah, const float* __restrict__ x,
            const int* __restrict__ idx, float* __restrict__ out) {
    int b = blockIdx.x / 57, tile = blockIdx.x % 57;
    int l0 = tile * 16;
    int tid = threadIdx.x, lane = tid & 63, w = tid >> 6;
    int n16 = lane & 15, quad = lane >> 4;

    __shared__ _Float16 pbuf[16][KPAD];
    __shared__ float rmx[4][16], rsm[4][16], rstat[16], rinv[16];

    // zero P pad columns 912..927 (avoid NaN garbage entering MFMA)
    pbuf[tid >> 4][LPAD + (tid & 15)] = (_Float16)0.f;

    // A-frag for GEMM1: A[m=lane&15][k=quad*8+j] = e1[l0+m][c-chunk]
    half8 afrag = *(const half8*)(e1T + ((size_t)b*LPAD + l0 + n16)*32 + quad*8);

    // GEMM1: wave w owns m-tiles t = w + 4*i
    float4v sv[15];
    const int nt = (w == 0) ? 15 : 14;   // 57 tiles total
    #pragma unroll
    for (int i = 0; i < 15; ++i) {
        if (i < nt) {
            int t = w + 4*i;
            half8 bfrag = *(const half8*)(e2T + ((size_t)b*LPAD + t*16 + n16)*32 + quad*8);
            float4v z = {0.f, 0.f, 0.f, 0.f};
            sv[i] = __builtin_amdgcn_mfma_f32_16x16x32_f16(afrag, bfrag, z, 0, 0, 0);
        }
    }
    // mask pad columns m=900..911 (tile 56, owned by wave 0 at i=14)
    if (w == 0 && n16 >= 4) { sv[14][0] = sv[14][1] = sv[14][2] = sv[14][3] = -1e30f; }

    // row max (per lane over own tiles, then xor-reduce across the 16 col-lanes)
    float mv0 = -1e30f, mv1 = -1e30f, mv2 = -1e30f, mv3 = -1e30f;
    #pragma unroll
    for (int i = 0; i < 15; ++i) if (i < nt) {
        mv0 = fmaxf(mv0, sv[i][0]); mv1 = fmaxf(mv1, sv[i][1]);
        mv2 = fmaxf(mv2, sv[i][2]); mv3 = fmaxf(mv3, sv[i][3]);
    }
    #pragma unroll
    for (int d = 1; d < 16; d <<= 1) {
        mv0 = fmaxf(mv0, __shfl_xor(mv0, d, 64));
        mv1 = fmaxf(mv1, __shfl_xor(mv1, d, 64));
        mv2 = fmaxf(mv2, __shfl_xor(mv2, d, 64));
        mv3 = fmaxf(mv3, __shfl_xor(mv3, d, 64));
    }
    if (n16 == 0) {
        rmx[w][quad*4+0] = mv0; rmx[w][quad*4+1] = mv1;
        rmx[w][quad*4+2] = mv2; rmx[w][quad*4+3] = mv3;
    }
    __syncthreads();
    if (tid < 16)
        rstat[tid] = fmaxf(fmaxf(rmx[0][tid], rmx[1][tid]), fmaxf(rmx[2][tid], rmx[3][tid]));
    __syncthreads();
    float rm0 = rstat[quad*4+0], rm1 = rstat[quad*4+1];
    float rm2 = rstat[quad*4+2], rm3 = rstat[quad*4+3];

    // exp, write unnormalized P to LDS, partial row sums
    float s0 = 0.f, s1 = 0.f, s2 = 0.f, s3 = 0.f;
    #pragma unroll
    for (int i = 0; i < 15; ++i) if (i < nt) {
        int m = (w + 4*i)*16 + n16;
        float e0 = __expf(sv[i][0] - rm0); s0 += e0; pbuf[quad*4+0][m] = (_Float16)e0;
        float e1 = __expf(sv[i][1] - rm1); s1 += e1; pbuf[quad*4+1][m] = (_Float16)e1;
        float e2 = __expf(sv[i][2] - rm2); s2 += e2; pbuf[quad*4+2][m] = (_Float16)e2;
        float e3 = __expf(sv[i][3] - rm3); s3 += e3; pbuf[quad*4+3][m] = (_Float16)e3;
    }
    #pragma unroll
    for (int d = 1; d < 16; d <<= 1) {
        s0 += __shfl_xor(s0, d, 64); s1 += __shfl_xor(s1, d, 64);
        s2 += __shfl_xor(s2, d, 64); s3 += __shfl_xor(s3, d, 64);
    }
    if (n16 == 0) {
        rsm[w][quad*4+0] = s0; rsm[w][quad*4+1] = s1;
        rsm[w][quad*4+2] = s2; rsm[w][quad*4+3] = s3;
    }
    __syncthreads();
    if (tid < 16)
        rinv[tid] = 1.f / (rsm[0][tid] + rsm[1][tid] + rsm[2][tid] + rsm[3][tid]);
    __syncthreads();   // also guarantees all pbuf writes are visible

    // GEMM2: wave w owns output col-tile c0 = 16*w. K = 928 = 28*32 + 32.
    // Two accumulator chains to halve exposed dependent-MFMA latency.
    float4v acc0 = {0.f, 0.f, 0.f, 0.f}, acc1 = {0.f, 0.f, 0.f, 0.f};
    const _Float16* eb = eah + ((size_t)b*CH + w*16 + n16)*KPAD + quad*8;
    const _Float16* pb = &pbuf[n16][quad*8];
    #pragma unroll
    for (int k0 = 0; k0 < 896; k0 += 64) {
        half8 af0 = *(const half8*)(pb + k0);
        half8 bf0 = *(const half8*)(eb + k0);
        acc0 = __builtin_amdgcn_mfma_f32_16x16x32_f16(af0, bf0, acc0, 0, 0, 0);
        half8 af1 = *(const half8*)(pb + k0 + 32);
        half8 bf1 = *(const half8*)(eb + k0 + 32);
        acc1 = __builtin_amdgcn_mfma_f32_16x16x32_f16(af1, bf1, acc1, 0, 0, 0);
    }
    {
        half8 af = *(const half8*)(pb + 896);
        half8 bf = *(const half8*)(eb + 896);
        acc0 = __builtin_amdgcn_mfma_f32_16x16x32_f16(af, bf, acc0, 0, 0, 0);
    }

    // epilogue: normalize, add original x value (== q), scatter
    int c = w*16 + n16;
    const float* xrow = x + (size_t)(b*CH + c)*HWTOT;
    float* orow = out + (size_t)(b*CH + c)*HWTOT;
    const int* irow = idx + b*LSEL;
    #pragma unroll
    for (int v = 0; v < 4; ++v) {
        int lr = quad*4 + v;
        int l = l0 + lr;
        if (l < LSEL) {
            int p = irow[l];
            float val = (acc0[v] + acc1[v]) * rinv[lr] + xrow[p];
            orow[p] = val;
        }
    }
}

extern "C" void kernel_launch(void* const* d_in, const int* in_sizes, int n_in,
                              void* d_out, int out_size, void* d_ws, size_t ws_size,
                              hipStream_t stream) {
    const float* x  = (const float*)d_in[0];
    const float* W1 = (const float*)d_in[1];
    const float* b1 = (const float*)d_in[2];
    const float* a1 = (const float*)d_in[3];
    const float* W2 = (const float*)d_in[4];
    const float* b2 = (const float*)d_in[5];
    const float* a2 = (const float*)d_in[6];
    const float* Wa = (const float*)d_in[7];
    const float* ba = (const float*)d_in[8];
    const float* aa = (const float*)d_in[9];
    float* out = (float*)d_out;
    char* ws = (char*)d_ws;

    int*          hist2 = (int*)         (ws + OFF_HIST2);
    uchar4*       z4    = (uchar4*)      (ws + OFF_Z);
    unsigned int* zu    = (unsigned int*)(ws + OFF_Z);
    int*          idx   = (int*)         (ws + OFF_IDX);
    _Float16*     e1T   = (_Float16*)    (ws + OFF_E1);
    _Float16*     e2T   = (_Float16*)    (ws + OFF_E2);
    _Float16*     eah   = (_Float16*)    (ws + OFF_EA);

    k_copy_count<<<NB*64, 256, 0, stream>>>(x, out, z4, hist2);
    k_select<<<NB, 1024, 0, stream>>>(zu, hist2, idx);
    k_e<<<E12_BLOCKS + EA_BLOCKS, 256, 0, stream>>>(x, idx, W1, b1, a1, W2, b2, a2,
                                                    Wa, ba, aa, e1T, e2T, eah);
    k_attn<<<NB*57, 256, 0, stream>>>(e1T, e2T, eah, x, idx, out);
}